// Round 2
// baseline (28500.192 us; speedup 1.0000x reference)
//
#include <hip/hip_runtime.h>
#include <math.h>

#define TT 512
#define BB 256
#define EE 300
#define KK 9
#define HH 256
#define GG 1024
#define NCH 8
#define CHS 64
#define NGRP 16
#define GBLK 16
#define BPG 32

#define XG_PER_GROUP (2048*1024)
#define RING_PER_GROUP (2*BPG*HH)
#define OFF_XG   ((size_t)0)
#define OFF_RING (OFF_XG + (size_t)NGRP*XG_PER_GROUP)          // 33,554,432
#define OFF_EMF  (OFF_RING + (size_t)NGRP*RING_PER_GROUP)      // +262,144
#define OFF_EMB2 (OFF_EMF + (size_t)BB*TT*KK)                  // +1,179,648
#define OFF_ND   (OFF_EMB2 + (size_t)BB*TT*KK)                 // +1,179,648
#define OFF_BAR  (OFF_ND + 256)                                // 256 uints

// ---- intra-group barrier: atomic counter + agent-scope fences ----
__device__ __forceinline__ void gbar(unsigned* c, unsigned target) {
  __syncthreads();
  if (threadIdx.x == 0) {
    __threadfence();
    __hip_atomic_fetch_add(c, 1u, __ATOMIC_ACQ_REL, __HIP_MEMORY_SCOPE_AGENT);
    while (__hip_atomic_load(c, __ATOMIC_ACQUIRE, __HIP_MEMORY_SCOPE_AGENT) < target)
      __builtin_amdgcn_s_sleep(2);
    __threadfence();
  }
  __syncthreads();
}

union SMem {
  struct { float As[60][132]; float Ws[60][132]; } xg;
  struct { float P[4][64][33]; float AL[32][260]; float Wk[260]; } st;
};

__global__ __launch_bounds__(256, 1) void lstm_persistent(
    const int* __restrict__ ids, const int* __restrict__ lens,
    const float* __restrict__ emb,
    const float* __restrict__ W_ih_f, const float* __restrict__ W_hh_f, const float* __restrict__ b_f,
    const float* __restrict__ W_ih_b, const float* __restrict__ W_hh_b, const float* __restrict__ b_b,
    const float* __restrict__ W_out, const float* __restrict__ b_out,
    float* __restrict__ ws)
{
  __shared__ SMem sm;
  __shared__ int tokid[128];

  const int tid  = threadIdx.x;
  const int g    = blockIdx.x & 15;    // group: blocks g, g+16, ... (same XCD under round-robin)
  const int sub  = blockIdx.x >> 4;    // 0..15 within group (j-tile)
  const int dir  = g >> 3;
  const int bgrp = g & 7;
  const int b0   = bgrp * BPG;

  const float* W_ih = dir ? W_ih_b : W_ih_f;
  const float* W_hh = dir ? W_hh_b : W_hh_f;
  const float* bias = dir ? b_b : b_f;

  float* xg   = ws + OFF_XG + (size_t)g * XG_PER_GROUP;
  float* ring = ws + OFF_RING + (size_t)g * RING_PER_GROUP;
  float* emis = ws + (dir ? OFF_EMB2 : OFF_EMF);
  unsigned* bar = (unsigned*)(ws + OFF_BAR) + g * 16;

  // epilogue cell ownership: (batch eb, j = sub*16 + ej and +8)
  const int eb = tid & 31;
  const int ej = tid >> 5;           // 0..7
  const int len_e = lens[b0 + eb];
  float c_e[2] = {0.f, 0.f};
  float h_e[2] = {0.f, 0.f};

  // GEMM ownership: wave wseg owns k-slice [wseg*64, +64); lane rrow owns gate-row
  const int wseg = __builtin_amdgcn_readfirstlane(tid >> 6);
  const int rrow = tid & 63;
  const int grow = (rrow >> 4) * 256 + sub * 16 + (rrow & 15);

  float bo = 0.f;
  if (sub < KK && dir == 0) bo = b_out[sub];

  int barcnt = 0;

  for (int ci = 0; ci < NCH; ++ci) {
    // ================= xg phase: this block computes token rows [sub*128, +128) =================
    if (tid < 128) {
      int m = sub * 128 + tid;
      int sl = m >> 5, bl = m & 31;
      int sidx = ci * CHS + sl;
      int t = dir ? (TT - 1 - sidx) : sidx;
      tokid[tid] = ids[t * BB + b0 + bl];
    }
    {
      const int ty = tid >> 4, tx = tid & 15;
      for (int nt = 0; nt < 8; ++nt) {
        float acc[8][8];
        #pragma unroll
        for (int a_ = 0; a_ < 8; ++a_)
          #pragma unroll
          for (int b_ = 0; b_ < 8; ++b_) acc[a_][b_] = 0.f;

        for (int kc = 0; kc < 5; ++kc) {
          __syncthreads();
          for (int i = tid; i < 128 * 15; i += 256) {
            int mm = i / 15, kq = i - mm * 15;
            float4 v = *(const float4*)&emb[(size_t)tokid[mm] * EE + kc * 60 + kq * 4];
            sm.xg.As[kq*4+0][mm] = v.x;
            sm.xg.As[kq*4+1][mm] = v.y;
            sm.xg.As[kq*4+2][mm] = v.z;
            sm.xg.As[kq*4+3][mm] = v.w;
          }
          for (int i = tid; i < 128 * 15; i += 256) {
            int nn = i / 15, kq = i - nn * 15;
            float4 v = *(const float4*)&W_ih[(size_t)(nt*128+nn) * EE + kc * 60 + kq * 4];
            sm.xg.Ws[kq*4+0][nn] = v.x;
            sm.xg.Ws[kq*4+1][nn] = v.y;
            sm.xg.Ws[kq*4+2][nn] = v.z;
            sm.xg.Ws[kq*4+3][nn] = v.w;
          }
          __syncthreads();
          for (int kk = 0; kk < 60; ++kk) {
            float4 a0 = *(const float4*)&sm.xg.As[kk][ty*8];
            float4 a1 = *(const float4*)&sm.xg.As[kk][ty*8+4];
            float4 w0 = *(const float4*)&sm.xg.Ws[kk][tx*8];
            float4 w1 = *(const float4*)&sm.xg.Ws[kk][tx*8+4];
            float av[8] = {a0.x,a0.y,a0.z,a0.w,a1.x,a1.y,a1.z,a1.w};
            float wv8[8] = {w0.x,w0.y,w0.z,w0.w,w1.x,w1.y,w1.z,w1.w};
            #pragma unroll
            for (int im = 0; im < 8; ++im)
              #pragma unroll
              for (int in = 0; in < 8; ++in) acc[im][in] += av[im] * wv8[in];
          }
        }
        // write out (+bias)
        #pragma unroll
        for (int im = 0; im < 8; ++im) {
          int m = ty*8 + im;
          int n = nt*128 + tx*8;
          float4 o0, o1;
          o0.x = acc[im][0] + bias[n+0]; o0.y = acc[im][1] + bias[n+1];
          o0.z = acc[im][2] + bias[n+2]; o0.w = acc[im][3] + bias[n+3];
          o1.x = acc[im][4] + bias[n+4]; o1.y = acc[im][5] + bias[n+5];
          o1.z = acc[im][6] + bias[n+6]; o1.w = acc[im][7] + bias[n+7];
          float* dst = &xg[(size_t)(sub*128 + m) * GG + n];
          *(float4*)dst = o0; *(float4*)(dst+4) = o1;
        }
      }
    }
    __syncthreads();

    // reload W_hh registers for this chunk (16 float4 = this thread's row x k-slice)
    float4 wv[16];
    #pragma unroll
    for (int i = 0; i < 16; ++i)
      wv[i] = *(const float4*)&W_hh[(size_t)grow * HH + wseg*64 + i*4];
    // stage W_out row for emission blocks
    if (sub < KK) {
      for (int i = tid; i < 64; i += 256)
        *(float4*)&sm.st.Wk[i*4] = *(const float4*)&W_out[(size_t)sub * 512 + dir*256 + i*4];
    }
    gbar(bar, (unsigned)(++barcnt) * GBLK);   // xg slice of every block visible to group

    // ================= 64 recurrent steps =================
    for (int sl = 0; sl < CHS; ++sl) {
      const int s = ci * CHS + sl;
      const int t = dir ? (TT - 1 - s) : s;
      const float* rprev = ring + ((s & 1) ^ 1) * (BPG * HH);
      float*       rcur  = ring + (s & 1) * (BPG * HH);

      // prefetch this thread's xg gate pre-activations
      float xv0[4], xv1[4];
      {
        const float* xrow = xg + (size_t)(sl*BPG + eb) * GG + sub*16;
        #pragma unroll
        for (int q = 0; q < 4; ++q) { xv0[q] = xrow[q*256 + ej]; xv1[q] = xrow[q*256 + ej + 8]; }
      }

      // ---- GEMM partials: pacc(b) = W_hh[grow, kslice] . h_prev[b, kslice] ----
      if (s > 0) {
        const float* hbase = rprev + wseg * 64;
        #pragma unroll 2
        for (int b = 0; b < BPG; ++b) {
          const float* hb = hbase + b * HH;
          float a0 = 0.f, a1 = 0.f, a2 = 0.f, a3 = 0.f;
          #pragma unroll
          for (int i = 0; i < 16; ++i) {
            float4 h4 = *(const float4*)&hb[i*4];   // wave-uniform address -> broadcast load
            a0 += wv[i].x * h4.x; a1 += wv[i].y * h4.y;
            a2 += wv[i].z * h4.z; a3 += wv[i].w * h4.w;
          }
          sm.st.P[wseg][rrow][b] = (a0 + a1) + (a2 + a3);
        }
      } else {
        for (int b = 0; b < BPG; ++b) sm.st.P[wseg][rrow][b] = 0.f;
      }
      // stage h_prev for emission blocks
      if (sub < KK && s > 0) {
        for (int i = tid; i < 2048; i += 256) {
          int bl = i >> 6, k4 = i & 63;
          *(float4*)&sm.st.AL[bl][k4*4] = *(const float4*)&rprev[bl*HH + k4*4];
        }
      }
      __syncthreads();

      // ---- combine partials + gates + state update ----
      {
        #pragma unroll
        for (int h2 = 0; h2 < 2; ++h2) {
          int jj = ej + h2*8;
          float gt[4];
          #pragma unroll
          for (int q = 0; q < 4; ++q) {
            int r = q*16 + jj;
            gt[q] = (h2 ? xv1[q] : xv0[q])
                  + sm.st.P[0][r][eb] + sm.st.P[1][r][eb]
                  + sm.st.P[2][r][eb] + sm.st.P[3][r][eb];
          }
          float si = 1.f / (1.f + expf(-gt[0]));
          float sf = 1.f / (1.f + expf(-gt[1]));
          float so = 1.f / (1.f + expf(-gt[3]));
          float cn = sf * c_e[h2] + si * tanhf(gt[2]);
          float hn = so * tanhf(cn);
          bool m = t < len_e;
          float ho = m ? hn : h_e[h2];
          float co = m ? cn : c_e[h2];
          h_e[h2] = ho; c_e[h2] = co;
          rcur[eb * HH + sub*16 + jj] = ho;
        }
      }

      // ---- emission for previous timestep (blocks sub<9) ----
      if (sub < KK && s > 0) {
        const int ebl = tid >> 3, part = tid & 7;
        float r = 0.f;
        #pragma unroll
        for (int u = 0; u < 8; ++u) {
          float4 h4 = *(const float4*)&sm.st.AL[ebl][part*32 + u*4];
          float4 w4 = *(const float4*)&sm.st.Wk[part*32 + u*4];
          r += h4.x*w4.x + h4.y*w4.y + h4.z*w4.z + h4.w*w4.w;
        }
        r += __shfl_down(r, 4); r += __shfl_down(r, 2); r += __shfl_down(r, 1);
        if (part == 0) {
          int tp = dir ? t + 1 : t - 1;
          emis[((size_t)(b0 + ebl) * TT + tp) * KK + sub] = r + bo;
        }
      }

      gbar(bar, (unsigned)(++barcnt) * GBLK);
    }
  }

  // ================= final emission for the last processed timestep =================
  if (sub < KK) {
    const float* rlast = ring + (BPG * HH);   // slot (TT-1)&1 == 1
    for (int i = tid; i < 2048; i += 256) {
      int bl = i >> 6, k4 = i & 63;
      *(float4*)&sm.st.AL[bl][k4*4] = *(const float4*)&rlast[bl*HH + k4*4];
    }
    __syncthreads();
    const int ebl = tid >> 3, part = tid & 7;
    float r = 0.f;
    #pragma unroll
    for (int u = 0; u < 8; ++u) {
      float4 h4 = *(const float4*)&sm.st.AL[ebl][part*32 + u*4];
      float4 w4 = *(const float4*)&sm.st.Wk[part*32 + u*4];
      r += h4.x*w4.x + h4.y*w4.y + h4.z*w4.z + h4.w*w4.w;
    }
    r += __shfl_down(r, 4); r += __shfl_down(r, 2); r += __shfl_down(r, 1);
    if (part == 0) {
      int tp = dir ? 0 : TT - 1;
      emis[((size_t)(b0 + ebl) * TT + tp) * KK + sub] = r + bo;
    }
  }
}

// ---------------- CRF: identical numerics to round 1; emissions = emis_f + emis_b ----------------
__global__ __launch_bounds__(64) void crf_kernel(
    const float* __restrict__ emis_f, const float* __restrict__ emis_b2,
    const int* __restrict__ labels, const int* __restrict__ lens,
    const float* __restrict__ start_trans, const float* __restrict__ end_trans,
    const float* __restrict__ trans,
    float* __restrict__ numden, float* __restrict__ outp)
{
  const int b = blockIdx.x;
  const int lane = threadIdx.x;
  __shared__ __align__(16) float em[TT * KK];
  __shared__ unsigned char hist[TT * KK];
  const float4* ef = (const float4*)(emis_f + (size_t)b * TT * KK);
  const float4* eb = (const float4*)(emis_b2 + (size_t)b * TT * KK);
  for (int i = lane; i < TT*KK/4; i += 64) {
    float4 a = ef[i], c = eb[i];
    float4 o; o.x = a.x+c.x; o.y = a.y+c.y; o.z = a.z+c.z; o.w = a.w+c.w;
    ((float4*)em)[i] = o;
  }
  const int len = lens[b];
  const int k = lane < KK ? lane : KK-1;
  float tc[KK];
  #pragma unroll
  for (int jj = 0; jj < KK; ++jj) tc[jj] = trans[jj*KK + k];
  __syncthreads();

  float nacc = 0.f;
  for (int t = lane; t < TT; t += 64) {
    int lt = labels[t*BB + b];
    if (t == 0) nacc += start_trans[lt] + em[lt];
    else if (t < len) nacc += trans[labels[(t-1)*BB + b]*KK + lt] + em[t*KK + lt];
  }
  if (lane == 0) nacc += end_trans[labels[(size_t)(len-1)*BB + b]];
  #pragma unroll
  for (int off = 32; off; off >>= 1) nacc += __shfl_down(nacc, off);

  float alpha[KK], score[KK];
  #pragma unroll
  for (int jj = 0; jj < KK; ++jj) {
    float v = start_trans[jj] + em[jj];
    alpha[jj] = v; score[jj] = v;
  }
  for (int t = 1; t < TT; ++t) {
    float av[KK]; float mx = -1e30f;
    #pragma unroll
    for (int jj = 0; jj < KK; ++jj) { av[jj] = alpha[jj] + tc[jj]; mx = fmaxf(mx, av[jj]); }
    float s = 0.f;
    #pragma unroll
    for (int jj = 0; jj < KK; ++jj) s += expf(av[jj] - mx);
    float e_tk = em[t*KK + k];
    float na = mx + logf(s) + e_tk;
    float best = -1e30f; int bj = 0;
    #pragma unroll
    for (int jj = 0; jj < KK; ++jj) {
      float sv = score[jj] + tc[jj];
      if (sv > best) { best = sv; bj = jj; }
    }
    float ns = best + e_tk;
    bool msk = t < len;
    na = msk ? na : alpha[k];
    ns = msk ? ns : score[k];
    if (lane < KK) hist[(t-1)*KK + lane] = (unsigned char)bj;
    #pragma unroll
    for (int jj = 0; jj < KK; ++jj) { alpha[jj] = __shfl(na, jj); score[jj] = __shfl(ns, jj); }
  }
  float dm = -1e30f;
  #pragma unroll
  for (int jj = 0; jj < KK; ++jj) dm = fmaxf(dm, alpha[jj] + end_trans[jj]);
  float dsum = 0.f;
  #pragma unroll
  for (int jj = 0; jj < KK; ++jj) dsum += expf(alpha[jj] + end_trans[jj] - dm);
  float denom = dm + logf(dsum);
  int bl_ = 0; float bs = -1e30f;
  #pragma unroll
  for (int jj = 0; jj < KK; ++jj) {
    float v = score[jj] + end_trans[jj];
    if (v > bs) { bs = v; bl_ = jj; }
  }
  if (lane == 0) numden[b] = nacc - denom;
  __syncthreads();
  if (lane == 0) {
    int tag = bl_;
    outp[1 + (size_t)(TT-1)*BB + b] = ((TT-1) < len) ? (float)bl_ : 0.f;
    for (int s = TT-2; s >= 0; --s) {
      tag = ((s+1) < len) ? (int)hist[s*KK + tag] : bl_;
      outp[1 + (size_t)s*BB + b] = (s < len) ? (float)tag : 0.f;
    }
  }
}

__global__ __launch_bounds__(256) void loss_reduce_kernel(
    const float* __restrict__ numden, float* __restrict__ out)
{
  __shared__ float sh[256];
  int tid = threadIdx.x;
  sh[tid] = numden[tid];
  __syncthreads();
  for (int s = 128; s > 0; s >>= 1) {
    if (tid < s) sh[tid] += sh[tid + s];
    __syncthreads();
  }
  if (tid == 0) out[0] = -sh[0];
}

extern "C" void kernel_launch(void* const* d_in, const int* in_sizes, int n_in,
                              void* d_out, int out_size, void* d_ws, size_t ws_size,
                              hipStream_t stream)
{
  const int*   ids    = (const int*)d_in[0];
  const int*   lens   = (const int*)d_in[1];
  const int*   labels = (const int*)d_in[2];
  const float* emb    = (const float*)d_in[3];
  const float* W_ih_f = (const float*)d_in[4];
  const float* W_hh_f = (const float*)d_in[5];
  const float* b_f    = (const float*)d_in[6];
  const float* W_ih_b = (const float*)d_in[7];
  const float* W_hh_b = (const float*)d_in[8];
  const float* b_b    = (const float*)d_in[9];
  const float* W_out  = (const float*)d_in[10];
  const float* b_out  = (const float*)d_in[11];
  const float* s_tr   = (const float*)d_in[12];
  const float* e_tr   = (const float*)d_in[13];
  const float* trans  = (const float*)d_in[14];
  float* out = (float*)d_out;

  float* ws = (float*)d_ws;
  float* emis_f = ws + OFF_EMF;
  float* emis_b = ws + OFF_EMB2;
  float* numden = ws + OFF_ND;

  // zero the barrier counters (poisoned 0xAA otherwise; monotonic targets need 0 start)
  hipMemsetAsync((char*)d_ws + OFF_BAR * sizeof(float), 0, NGRP * 16 * sizeof(unsigned), stream);

  lstm_persistent<<<256, 256, 0, stream>>>(ids, lens, emb,
      W_ih_f, W_hh_f, b_f, W_ih_b, W_hh_b, b_b, W_out, b_out, ws);

  crf_kernel<<<BB, 64, 0, stream>>>(emis_f, emis_b, labels, lens, s_tr, e_tr, trans, numden, out);
  loss_reduce_kernel<<<1, 256, 0, stream>>>(numden, out);
}

// Round 3
// 14249.353 us; speedup vs baseline: 2.0001x; 2.0001x over previous
//
#include <hip/hip_runtime.h>
#include <math.h>

#define TT 512
#define BB 256
#define EE 300
#define KK 9
#define HH 256
#define GG 1024
#define CHS 64            // timesteps per xg chunk
#define NCH (TT/CHS)

// workspace offsets (floats)
#define OFF_XG  ((size_t)0)                         // 2 * 16384 * 1024
#define OFF_HB  (OFF_XG + (size_t)2*CHS*BB*GG)      // hbuf: 2 dir * 2 par * 256 * 256
#define OFF_C   (OFF_HB + (size_t)2*2*BB*HH)        // cws: 2 * 256 * 256
#define OFF_EF  (OFF_C  + (size_t)2*BB*HH)          // emis fwd: 256*512*9
#define OFF_EB  (OFF_EF + (size_t)BB*TT*KK)         // emis bwd
#define OFF_ND  (OFF_EB + (size_t)BB*TT*KK)         // numden: 256

// ---------------- xg chunk GEMM: both dirs, 256 blocks x 128 tokens x 1024 gates ----------------
__global__ __launch_bounds__(256) void gemm_xg_kernel(
    const int* __restrict__ ids, const float* __restrict__ emb,
    const float* __restrict__ W_ih_f, const float* __restrict__ W_ih_b,
    const float* __restrict__ b_f, const float* __restrict__ b_b,
    float* __restrict__ xgc, int ci)
{
  __shared__ float As[60][132];
  __shared__ float Ws[60][132];
  __shared__ int tokid[128];
  const int tid = threadIdx.x;
  const int dir = blockIdx.x >> 7;
  const int r   = blockIdx.x & 127;
  const float* W_ih = dir ? W_ih_b : W_ih_f;
  const float* bias = dir ? b_b : b_f;

  if (tid < 128) {
    int m = r * 128 + tid;               // chunk-local token row (sl*256 + bl)
    int sidx = ci * CHS + (m >> 8);
    int t = dir ? (TT - 1 - sidx) : sidx;
    tokid[tid] = ids[t * BB + (m & 255)];
  }
  __syncthreads();

  const int ty = tid >> 4, tx = tid & 15;
  for (int nt = 0; nt < 8; ++nt) {
    float acc[8][8];
    #pragma unroll
    for (int a_ = 0; a_ < 8; ++a_)
      #pragma unroll
      for (int b_ = 0; b_ < 8; ++b_) acc[a_][b_] = 0.f;

    for (int kc = 0; kc < 5; ++kc) {
      __syncthreads();
      for (int i = tid; i < 128 * 15; i += 256) {
        int mm = i / 15, kq = i - mm * 15;
        float4 v = *(const float4*)&emb[(size_t)tokid[mm] * EE + kc * 60 + kq * 4];
        As[kq*4+0][mm] = v.x; As[kq*4+1][mm] = v.y;
        As[kq*4+2][mm] = v.z; As[kq*4+3][mm] = v.w;
      }
      for (int i = tid; i < 128 * 15; i += 256) {
        int nn = i / 15, kq = i - nn * 15;
        float4 v = *(const float4*)&W_ih[(size_t)(nt*128+nn) * EE + kc * 60 + kq * 4];
        Ws[kq*4+0][nn] = v.x; Ws[kq*4+1][nn] = v.y;
        Ws[kq*4+2][nn] = v.z; Ws[kq*4+3][nn] = v.w;
      }
      __syncthreads();
      for (int kk = 0; kk < 60; ++kk) {
        float4 a0 = *(const float4*)&As[kk][ty*8];
        float4 a1 = *(const float4*)&As[kk][ty*8+4];
        float4 w0 = *(const float4*)&Ws[kk][tx*8];
        float4 w1 = *(const float4*)&Ws[kk][tx*8+4];
        float av[8] = {a0.x,a0.y,a0.z,a0.w,a1.x,a1.y,a1.z,a1.w};
        float wv8[8] = {w0.x,w0.y,w0.z,w0.w,w1.x,w1.y,w1.z,w1.w};
        #pragma unroll
        for (int im = 0; im < 8; ++im)
          #pragma unroll
          for (int in = 0; in < 8; ++in) acc[im][in] += av[im] * wv8[in];
      }
    }
    #pragma unroll
    for (int im = 0; im < 8; ++im) {
      int m = ty*8 + im;
      int n = nt*128 + tx*8;
      float4 o0, o1;
      o0.x = acc[im][0] + bias[n+0]; o0.y = acc[im][1] + bias[n+1];
      o0.z = acc[im][2] + bias[n+2]; o0.w = acc[im][3] + bias[n+3];
      o1.x = acc[im][4] + bias[n+4]; o1.y = acc[im][5] + bias[n+5];
      o1.z = acc[im][6] + bias[n+6]; o1.w = acc[im][7] + bias[n+7];
      float* dst = &xgc[(size_t)(dir*16384 + r*128 + m) * GG + n];
      *(float4*)dst = o0; *(float4*)(dst+4) = o1;
    }
  }
}

// ---------------- one timestep, both dirs: 256 blocks (dir x 8 btile x 16 jtile) ----------------
// Block: 32 batches x (4 gates x 16 j). W_hh slice in VGPRs; h_prev in LDS; fused emission(t-1).
__global__ __launch_bounds__(256) void lstm_step(
    const float* __restrict__ xgc,
    const float* __restrict__ Whhf, const float* __restrict__ Whhb,
    const float* __restrict__ Wout, const float* __restrict__ bout,
    const int* __restrict__ lens,
    float* __restrict__ hbuf, float* __restrict__ cws,
    float* __restrict__ emisf, float* __restrict__ emisb,
    int s, int sl)
{
  __shared__ float HT[32][260];    // h_prev: 32 batches x 256 k (pad 4)
  __shared__ float P[4][64][33];   // partials: kseg x gate-row x batch (pad 1)
  __shared__ float Wk[256];        // W_out row (this jt) for fused emission

  const int tid = threadIdx.x;
  const int bid = blockIdx.x;
  const int dir = bid >> 7;
  const int rr_ = bid & 127;
  const int jt = rr_ & 15;
  const int bt = rr_ >> 4;
  const int b0 = bt * 32;
  const int t = dir ? (TT - 1 - s) : s;
  const int first = (s == 0);

  const float* Whh = dir ? Whhb : Whhf;
  float* emis = dir ? emisb : emisf;
  const float* hprev = hbuf + (size_t)((dir*2 + (s & 1)) * BB) * HH;
  float*       hout  = hbuf + (size_t)((dir*2 + ((s & 1) ^ 1)) * BB) * HH;

  // ---- stage h_prev tile (coalesced), W_out row ----
  if (!first) {
    for (int i = tid; i < 2048; i += 256) {
      int bl = i >> 6, k4 = i & 63;
      *(float4*)&HT[bl][k4*4] = *(const float4*)&hprev[(size_t)(b0+bl)*HH + k4*4];
    }
  }
  if (jt < KK && tid < 64)
    *(float4*)&Wk[tid*4] = *(const float4*)&Wout[(size_t)jt*512 + dir*256 + tid*4];

  // ---- W_hh slice into VGPRs: lane rrow -> gate row, wave wseg -> k-slice of 64 ----
  const int wseg = tid >> 6;
  const int rrow = tid & 63;
  const int grow = (rrow >> 4) * 256 + jt * 16 + (rrow & 15);
  float4 wv[16];
  if (!first) {
    #pragma unroll
    for (int i = 0; i < 16; ++i)
      wv[i] = *(const float4*)&Whh[(size_t)grow * HH + wseg*64 + i*4];
  }
  __syncthreads();

  // ---- GEMM partials: P[wseg][rrow][b] = W[grow, kslice] . h[b, kslice] ----
  if (!first) {
    #pragma unroll 2
    for (int b = 0; b < 32; ++b) {
      const float* hb = &HT[b][wseg*64];     // wave-uniform -> LDS broadcast
      float a0 = 0.f, a1 = 0.f, a2 = 0.f, a3 = 0.f;
      #pragma unroll
      for (int i = 0; i < 16; ++i) {
        float4 h4 = *(const float4*)&hb[i*4];
        a0 += wv[i].x * h4.x; a1 += wv[i].y * h4.y;
        a2 += wv[i].z * h4.z; a3 += wv[i].w * h4.w;
      }
      P[wseg][rrow][b] = (a0 + a1) + (a2 + a3);
    }
  }
  __syncthreads();

  // ---- combine + gates + state update: thread (eb, jj) owns (batch, 2 j's) ----
  {
    const int eb = tid & 31;
    const int jj = tid >> 5;              // 0..7
    const int len_b = lens[b0 + eb];
    const bool m = t < len_b;
    const float* xrow = xgc + ((size_t)(dir*16384 + sl*BB) + b0 + eb) * GG + jt*16;
    #pragma unroll
    for (int h2 = 0; h2 < 2; ++h2) {
      const int jl = jj + h2*8;
      float gt[4];
      #pragma unroll
      for (int q = 0; q < 4; ++q) {
        float v = xrow[q*256 + jl];
        if (!first)
          v += P[0][q*16+jl][eb] + P[1][q*16+jl][eb]
             + P[2][q*16+jl][eb] + P[3][q*16+jl][eb];
        gt[q] = v;
      }
      float si = 1.f / (1.f + expf(-gt[0]));
      float sf = 1.f / (1.f + expf(-gt[1]));
      float so = 1.f / (1.f + expf(-gt[3]));
      float c_old = first ? 0.f : cws[((size_t)dir*BB + b0 + eb) * HH + jt*16 + jl];
      float h_old = first ? 0.f : HT[eb][jt*16 + jl];
      float cn = sf * c_old + si * tanhf(gt[2]);
      float hn = so * tanhf(cn);
      float ho = m ? hn : h_old;
      float co = m ? cn : c_old;
      hout[(size_t)(b0 + eb) * HH + jt*16 + jl] = ho;
      cws[((size_t)dir*BB + b0 + eb) * HH + jt*16 + jl] = co;
    }
  }

  // ---- fused emission for previous timestep (blocks jt<9; h_prev still in HT) ----
  if (jt < KK && !first) {
    const int ebb = tid >> 3, seg = tid & 7;
    float r = 0.f;
    #pragma unroll
    for (int u = 0; u < 8; ++u) {
      int c = (u*8 + seg) * 4;            // interleaved: avoids 32-float bank degeneracy
      float4 h4 = *(const float4*)&HT[ebb][c];
      float4 w4 = *(const float4*)&Wk[c];
      r += h4.x*w4.x + h4.y*w4.y + h4.z*w4.z + h4.w*w4.w;
    }
    r += __shfl_down(r, 4); r += __shfl_down(r, 2); r += __shfl_down(r, 1);
    if (seg == 0) {
      int tprev = dir ? t + 1 : t - 1;
      emis[((size_t)(b0 + ebb) * TT + tprev) * KK + jt] = r + (dir ? 0.f : bout[jt]);
    }
  }
}

// ---------------- emission for the final processed timestep of each dir ----------------
__global__ __launch_bounds__(256) void final_emis_kernel(
    const float* __restrict__ hbuf, const float* __restrict__ Wout,
    const float* __restrict__ bout, float* __restrict__ emisf, float* __restrict__ emisb)
{
  __shared__ float HT[32][260];
  const int tid = threadIdx.x;
  const int dir = blockIdx.x >> 3;
  const int bt = blockIdx.x & 7;
  const int b0 = bt * 32;
  const float* hlast = hbuf + (size_t)((dir*2 + 0) * BB) * HH;   // parity after s=511
  for (int i = tid; i < 2048; i += 256) {
    int bl = i >> 6, k4 = i & 63;
    *(float4*)&HT[bl][k4*4] = *(const float4*)&hlast[(size_t)(b0+bl)*HH + k4*4];
  }
  __syncthreads();
  float* emis = dir ? emisb : emisf;
  const int tlast = dir ? 0 : TT - 1;
  const int ebb = tid >> 3, seg = tid & 7;
  for (int k = 0; k < KK; ++k) {
    float r = 0.f;
    #pragma unroll
    for (int u = 0; u < 8; ++u) {
      int c = (u*8 + seg) * 4;
      float4 h4 = *(const float4*)&HT[ebb][c];
      float4 w4 = *(const float4*)&Wout[(size_t)k*512 + dir*256 + c];
      r += h4.x*w4.x + h4.y*w4.y + h4.z*w4.z + h4.w*w4.w;
    }
    r += __shfl_down(r, 4); r += __shfl_down(r, 2); r += __shfl_down(r, 1);
    if (seg == 0)
      emis[((size_t)(b0 + ebb) * TT + tlast) * KK + k] = r + (dir ? 0.f : bout[k]);
  }
}

// ---------------- CRF (identical numerics to rounds 1/2) ----------------
__global__ __launch_bounds__(64) void crf_kernel(
    const float* __restrict__ emis_f, const float* __restrict__ emis_b2,
    const int* __restrict__ labels, const int* __restrict__ lens,
    const float* __restrict__ start_trans, const float* __restrict__ end_trans,
    const float* __restrict__ trans,
    float* __restrict__ numden, float* __restrict__ outp)
{
  const int b = blockIdx.x;
  const int lane = threadIdx.x;
  __shared__ __align__(16) float em[TT * KK];
  __shared__ unsigned char hist[TT * KK];
  const float4* ef = (const float4*)(emis_f + (size_t)b * TT * KK);
  const float4* eb = (const float4*)(emis_b2 + (size_t)b * TT * KK);
  for (int i = lane; i < TT*KK/4; i += 64) {
    float4 a = ef[i], c = eb[i];
    float4 o; o.x = a.x+c.x; o.y = a.y+c.y; o.z = a.z+c.z; o.w = a.w+c.w;
    ((float4*)em)[i] = o;
  }
  const int len = lens[b];
  const int k = lane < KK ? lane : KK-1;
  float tc[KK];
  #pragma unroll
  for (int jj = 0; jj < KK; ++jj) tc[jj] = trans[jj*KK + k];
  __syncthreads();

  float nacc = 0.f;
  for (int t = lane; t < TT; t += 64) {
    int lt = labels[t*BB + b];
    if (t == 0) nacc += start_trans[lt] + em[lt];
    else if (t < len) nacc += trans[labels[(t-1)*BB + b]*KK + lt] + em[t*KK + lt];
  }
  if (lane == 0) nacc += end_trans[labels[(size_t)(len-1)*BB + b]];
  #pragma unroll
  for (int off = 32; off; off >>= 1) nacc += __shfl_down(nacc, off);

  float alpha[KK], score[KK];
  #pragma unroll
  for (int jj = 0; jj < KK; ++jj) {
    float v = start_trans[jj] + em[jj];
    alpha[jj] = v; score[jj] = v;
  }
  for (int t = 1; t < TT; ++t) {
    float av[KK]; float mx = -1e30f;
    #pragma unroll
    for (int jj = 0; jj < KK; ++jj) { av[jj] = alpha[jj] + tc[jj]; mx = fmaxf(mx, av[jj]); }
    float ssum = 0.f;
    #pragma unroll
    for (int jj = 0; jj < KK; ++jj) ssum += expf(av[jj] - mx);
    float e_tk = em[t*KK + k];
    float na = mx + logf(ssum) + e_tk;
    float best = -1e30f; int bj = 0;
    #pragma unroll
    for (int jj = 0; jj < KK; ++jj) {
      float sv = score[jj] + tc[jj];
      if (sv > best) { best = sv; bj = jj; }
    }
    float ns = best + e_tk;
    bool msk = t < len;
    na = msk ? na : alpha[k];
    ns = msk ? ns : score[k];
    if (lane < KK) hist[(t-1)*KK + lane] = (unsigned char)bj;
    #pragma unroll
    for (int jj = 0; jj < KK; ++jj) { alpha[jj] = __shfl(na, jj); score[jj] = __shfl(ns, jj); }
  }
  float dm = -1e30f;
  #pragma unroll
  for (int jj = 0; jj < KK; ++jj) dm = fmaxf(dm, alpha[jj] + end_trans[jj]);
  float dsum = 0.f;
  #pragma unroll
  for (int jj = 0; jj < KK; ++jj) dsum += expf(alpha[jj] + end_trans[jj] - dm);
  float denom = dm + logf(dsum);
  int bl_ = 0; float bs = -1e30f;
  #pragma unroll
  for (int jj = 0; jj < KK; ++jj) {
    float v = score[jj] + end_trans[jj];
    if (v > bs) { bs = v; bl_ = jj; }
  }
  if (lane == 0) numden[b] = nacc - denom;
  __syncthreads();
  if (lane == 0) {
    int tag = bl_;
    outp[1 + (size_t)(TT-1)*BB + b] = ((TT-1) < len) ? (float)bl_ : 0.f;
    for (int s = TT-2; s >= 0; --s) {
      tag = ((s+1) < len) ? (int)hist[s*KK + tag] : bl_;
      outp[1 + (size_t)s*BB + b] = (s < len) ? (float)tag : 0.f;
    }
  }
}

__global__ __launch_bounds__(256) void loss_reduce_kernel(
    const float* __restrict__ numden, float* __restrict__ out)
{
  __shared__ float sh[256];
  int tid = threadIdx.x;
  sh[tid] = numden[tid];
  __syncthreads();
  for (int s = 128; s > 0; s >>= 1) {
    if (tid < s) sh[tid] += sh[tid + s];
    __syncthreads();
  }
  if (tid == 0) out[0] = -sh[0];
}

extern "C" void kernel_launch(void* const* d_in, const int* in_sizes, int n_in,
                              void* d_out, int out_size, void* d_ws, size_t ws_size,
                              hipStream_t stream)
{
  const int*   ids    = (const int*)d_in[0];
  const int*   lens   = (const int*)d_in[1];
  const int*   labels = (const int*)d_in[2];
  const float* emb    = (const float*)d_in[3];
  const float* W_ih_f = (const float*)d_in[4];
  const float* W_hh_f = (const float*)d_in[5];
  const float* b_f    = (const float*)d_in[6];
  const float* W_ih_b = (const float*)d_in[7];
  const float* W_hh_b = (const float*)d_in[8];
  const float* b_b    = (const float*)d_in[9];
  const float* W_out  = (const float*)d_in[10];
  const float* b_out  = (const float*)d_in[11];
  const float* s_tr   = (const float*)d_in[12];
  const float* e_tr   = (const float*)d_in[13];
  const float* trans  = (const float*)d_in[14];
  float* out = (float*)d_out;

  float* ws = (float*)d_ws;
  float* xgc    = ws + OFF_XG;
  float* hbuf   = ws + OFF_HB;
  float* cws    = ws + OFF_C;
  float* emis_f = ws + OFF_EF;
  float* emis_b = ws + OFF_EB;
  float* numden = ws + OFF_ND;

  for (int ci = 0; ci < NCH; ++ci) {
    gemm_xg_kernel<<<256, 256, 0, stream>>>(ids, emb, W_ih_f, W_ih_b, b_f, b_b, xgc, ci);
    for (int sl = 0; sl < CHS; ++sl) {
      int s = ci * CHS + sl;
      lstm_step<<<256, 256, 0, stream>>>(xgc, W_hh_f, W_hh_b, W_out, b_out, lens,
                                         hbuf, cws, emis_f, emis_b, s, sl);
    }
  }
  final_emis_kernel<<<16, 256, 0, stream>>>(hbuf, W_out, b_out, emis_f, emis_b);
  crf_kernel<<<BB, 64, 0, stream>>>(emis_f, emis_b, labels, lens, s_tr, e_tr, trans, numden, out);
  loss_reduce_kernel<<<1, 256, 0, stream>>>(numden, out);
}